// Round 1
// baseline (396.207 us; speedup 1.0000x reference)
//
#include <hip/hip_runtime.h>
#include <math.h>

// Problem constants (from reference): NE=1e6, NR=1000, D=32, B=2^20, CURV=1
#define NR_ 1000
#define D_ 32
#define HALF_ 16
#define EMB_DIM 33          // entity_emb row: [x0, spatial(32)]
#define TAB_STRIDE 68       // floats per precomputed relation row (272 B, 16B-aligned)

// ---------------------------------------------------------------------------
// Kernel 1: per-relation precompute (1000 relations, trivial cost).
// Layout per relation r (68 floats):
//   [0:16)  c[j]  = cos(rot[j])
//   [16:32) s[j]  = sin(rot[j])
//   [32:64) kt[j] = (sinh(vn)/vn) * 0.1 * trans[j]
//   [64] cosh(rap0)  [65] sinh(rap0)  [66] cosh(vn)  [67] pad
// where vn = sqrt(max(0.01*||trans||^2, 1e-6)), rap0 = clip(boost[0],-2,2)
// ---------------------------------------------------------------------------
__global__ __launch_bounds__(256) void rel_precompute_kernel(
    const float* __restrict__ boost_w, const float* __restrict__ rot_w,
    const float* __restrict__ trans_w, float* __restrict__ tab) {
  int r = blockIdx.x * blockDim.x + threadIdx.x;
  if (r >= NR_) return;
  const float* ro = rot_w   + (size_t)r * D_;
  const float* tr = trans_w + (size_t)r * D_;
  float* o = tab + (size_t)r * TAB_STRIDE;
  #pragma unroll
  for (int j = 0; j < HALF_; ++j) {
    float th = ro[j];
    o[j]         = cosf(th);
    o[HALF_ + j] = sinf(th);
  }
  float s2 = 0.f;
  #pragma unroll
  for (int j = 0; j < D_; ++j) { float v = tr[j]; s2 = fmaf(v, v, s2); }
  float vn  = sqrtf(fmaxf(0.01f * s2, 1e-6f));
  float cvn = coshf(vn);
  float k   = sinhf(vn) / vn * 0.1f;
  #pragma unroll
  for (int j = 0; j < D_; ++j) o[2 * HALF_ + j] = k * tr[j];
  float rap = fminf(fmaxf(boost_w[(size_t)r * D_], -2.f), 2.f);
  o[64] = coshf(rap);
  o[65] = sinhf(rap);
  o[66] = cvn;
  o[67] = 0.f;
}

// ---------------------------------------------------------------------------
// Kernel 2: main scoring kernel. One thread per batch element.
// Algebra (verified against reference):
//   rotated[j]      = c[j]*sp[j]   - s[j]*sp[16+j]       (j<16)
//   rotated[16+j]   = s[j]*sp[j]   + c[j]*sp[16+j]
//   new_sp[0]       = x0*sinh(rap) + rotated[0]*cosh(rap); new_sp[j]=rotated[j] else
//   (h_boost time component is NEVER used downstream -> skip its sqrt)
//   res_sp[j]       = cosh(vn)*new_sp[j] + kt[j]
//   ht0             = sqrt(1 + ||res_sp||^2)
//   -inner          = ht0*t0 - dot(res_sp, t_sp)
//   dist            = acosh(max(-inner, 1+1e-6))
//   out             = -dist^2 + bias[h] + bias[t]
// ---------------------------------------------------------------------------
template<bool USE_TAB>
__global__ __launch_bounds__(256) void lorentz_main_kernel(
    const int* __restrict__ heads, const int* __restrict__ rels,
    const int* __restrict__ tails, const float* __restrict__ emb,
    const float* __restrict__ boost_w, const float* __restrict__ rot_w,
    const float* __restrict__ trans_w, const float* __restrict__ bias,
    const float* __restrict__ tab, float* __restrict__ out, int n) {
  int i = blockIdx.x * blockDim.x + threadIdx.x;
  if (i >= n) return;
  int hd = heads[i], rl = rels[i], tl = tails[i];
  const float* __restrict__ hrow = emb + (size_t)hd * EMB_DIM;
  const float* __restrict__ trow = emb + (size_t)tl * EMB_DIM;

  float c[HALF_], s[HALF_], kt[D_], c0, s0, cvn;
  if (USE_TAB) {
    const float4* __restrict__ T =
        reinterpret_cast<const float4*>(tab + (size_t)rl * TAB_STRIDE);
    #pragma unroll
    for (int q = 0; q < 4; ++q) {
      float4 v = T[q];
      c[4*q] = v.x; c[4*q+1] = v.y; c[4*q+2] = v.z; c[4*q+3] = v.w;
    }
    #pragma unroll
    for (int q = 0; q < 4; ++q) {
      float4 v = T[4 + q];
      s[4*q] = v.x; s[4*q+1] = v.y; s[4*q+2] = v.z; s[4*q+3] = v.w;
    }
    #pragma unroll
    for (int q = 0; q < 8; ++q) {
      float4 v = T[8 + q];
      kt[4*q] = v.x; kt[4*q+1] = v.y; kt[4*q+2] = v.z; kt[4*q+3] = v.w;
    }
    float4 v = T[16];
    c0 = v.x; s0 = v.y; cvn = v.z;
  } else {
    // Fallback if ws_size is too small for the relation table: inline math.
    const float* ro = rot_w   + (size_t)rl * D_;
    const float* tr = trans_w + (size_t)rl * D_;
    #pragma unroll
    for (int j = 0; j < HALF_; ++j) { float th = ro[j]; c[j] = cosf(th); s[j] = sinf(th); }
    float s2 = 0.f;
    #pragma unroll
    for (int j = 0; j < D_; ++j) { float v = tr[j]; s2 = fmaf(v, v, s2); }
    float vn = sqrtf(fmaxf(0.01f * s2, 1e-6f));
    cvn = coshf(vn);
    float k = sinhf(vn) / vn * 0.1f;
    #pragma unroll
    for (int j = 0; j < D_; ++j) kt[j] = k * tr[j];
    float rap = fminf(fmaxf(boost_w[(size_t)rl * D_], -2.f), 2.f);
    c0 = coshf(rap); s0 = sinhf(rap);
  }

  float x0 = hrow[0];
  float r[D_];
  #pragma unroll
  for (int j = 0; j < HALF_; ++j) {
    float a = hrow[1 + j];
    float b = hrow[1 + HALF_ + j];
    r[j]         = c[j] * a - s[j] * b;
    r[HALF_ + j] = s[j] * a + c[j] * b;
  }
  // Lorentz boost affects only spatial component 0 (using original x0):
  r[0] = fmaf(x0, s0, r[0] * c0);

  float t0 = trow[0];
  float n2 = 0.f, dot = 0.f;
  #pragma unroll
  for (int j = 0; j < D_; ++j) {
    float rs = fmaf(cvn, r[j], kt[j]);
    n2  = fmaf(rs, rs, n2);
    dot = fmaf(rs, trow[1 + j], dot);
  }
  float ht0 = sqrtf(1.f + n2);
  float neg_inner = fmaf(ht0, t0, -dot);          // -inner = ht0*t0 - dot
  float ic = fmaxf(neg_inner, 1.0f + 1e-6f);
  float dist = acoshf(ic);
  out[i] = bias[hd] + bias[tl] - dist * dist;
}

extern "C" void kernel_launch(void* const* d_in, const int* in_sizes, int n_in,
                              void* d_out, int out_size, void* d_ws, size_t ws_size,
                              hipStream_t stream) {
  const int*   heads  = (const int*)d_in[0];
  const int*   rels   = (const int*)d_in[1];
  const int*   tails  = (const int*)d_in[2];
  const float* emb    = (const float*)d_in[3];
  const float* boostw = (const float*)d_in[4];
  const float* rotw   = (const float*)d_in[5];
  const float* transw = (const float*)d_in[6];
  const float* bias   = (const float*)d_in[7];
  float* out = (float*)d_out;
  int n = in_sizes[0];  // B = 1048576

  size_t tab_bytes = (size_t)NR_ * TAB_STRIDE * sizeof(float);
  dim3 block(256);
  dim3 grid((n + 255) / 256);

  if (ws_size >= tab_bytes) {
    float* tab = (float*)d_ws;
    rel_precompute_kernel<<<dim3((NR_ + 255) / 256), block, 0, stream>>>(
        boostw, rotw, transw, tab);
    lorentz_main_kernel<true><<<grid, block, 0, stream>>>(
        heads, rels, tails, emb, boostw, rotw, transw, bias, tab, out, n);
  } else {
    lorentz_main_kernel<false><<<grid, block, 0, stream>>>(
        heads, rels, tails, emb, boostw, rotw, transw, bias, (const float*)nullptr, out, n);
  }
}

// Round 2
// 295.308 us; speedup vs baseline: 1.3417x; 1.3417x over previous
//
#include <hip/hip_runtime.h>
#include <math.h>

// Problem constants: NE=1e6, NR=1000, D=32, B=2^20, CURV=1
#define NR_ 1000
#define D_ 32
#define HALF_ 16
#define EMB_DIM 33          // entity row: [x0, spatial(32)] -> 132 B, 4B-aligned only
#define TAB_STRIDE 68       // precomputed relation row (272 B, 16B-aligned)
#define ROWF (64 * EMB_DIM) // 2112 floats staged per wave

// ---------------------------------------------------------------------------
// Kernel 1: per-relation precompute (1000 rows, trivial).
//   [0:16) cos(rot)  [16:32) sin(rot)  [32:64) (sinh(vn)/vn)*0.1*trans
//   [64] cosh(rap0) [65] sinh(rap0) [66] cosh(vn) [67] pad
// ---------------------------------------------------------------------------
__global__ __launch_bounds__(256) void rel_precompute_kernel(
    const float* __restrict__ boost_w, const float* __restrict__ rot_w,
    const float* __restrict__ trans_w, float* __restrict__ tab) {
  int r = blockIdx.x * blockDim.x + threadIdx.x;
  if (r >= NR_) return;
  const float* ro = rot_w   + (size_t)r * D_;
  const float* tr = trans_w + (size_t)r * D_;
  float* o = tab + (size_t)r * TAB_STRIDE;
  #pragma unroll
  for (int j = 0; j < HALF_; ++j) {
    float th = ro[j];
    o[j]         = cosf(th);
    o[HALF_ + j] = sinf(th);
  }
  float s2 = 0.f;
  #pragma unroll
  for (int j = 0; j < D_; ++j) { float v = tr[j]; s2 = fmaf(v, v, s2); }
  float vn  = sqrtf(fmaxf(0.01f * s2, 1e-6f));
  float k   = sinhf(vn) / vn * 0.1f;
  #pragma unroll
  for (int j = 0; j < D_; ++j) o[2 * HALF_ + j] = k * tr[j];
  float rap = fminf(fmaxf(boost_w[(size_t)r * D_], -2.f), 2.f);
  o[64] = coshf(rap);
  o[65] = sinhf(rap);
  o[66] = coshf(vn);
  o[67] = 0.f;
}

// ---------------------------------------------------------------------------
// Kernel 2: main scoring. Block=256 (4 waves); each wave owns 64 elements.
// Entity rows are staged into LDS wave-cooperatively (consecutive lanes ->
// consecutive addresses), converting 66 lane-divergent scalar gathers/thread
// into 66 mostly-coalesced wide loads/wave. Head phase and tail phase reuse
// the same LDS buffer (two-pass) to keep LDS at ~35 KB/block -> 4 blocks/CU.
// ---------------------------------------------------------------------------
__global__ __launch_bounds__(256) void lorentz_coop_kernel(
    const int* __restrict__ heads, const int* __restrict__ rels,
    const int* __restrict__ tails, const float* __restrict__ emb,
    const float* __restrict__ bias, const float* __restrict__ tab,
    float* __restrict__ out, int n) {
  __shared__ float lds_row[4][ROWF];   // 33792 B
  __shared__ int   lds_hidx[4][64];    // 1024 B
  __shared__ int   lds_tidx[4][64];    // 1024 B

  const int lane = threadIdx.x & 63;
  const int w    = threadIdx.x >> 6;
  const int gid  = blockIdx.x * 256 + threadIdx.x;
  const int i    = (gid < n) ? gid : (n - 1);   // clamp loads; store guarded

  const int hd = heads[i];
  const int rl = rels[i];
  const int tl = tails[i];
  lds_hidx[w][lane] = hd;
  lds_tidx[w][lane] = tl;

  // Issue bias + tab header early (independent, L2/L3-resident).
  const float b_h = bias[hd];
  const float b_t = bias[tl];
  const float4* __restrict__ T =
      reinterpret_cast<const float4*>(tab + (size_t)rl * TAB_STRIDE);

  float* __restrict__ rowbuf = lds_row[w];
  __syncthreads();  // B1: index arrays visible

  // ---- Phase A: stage 64 head rows (2112 floats) cooperatively ----
  #pragma unroll
  for (int k = 0; k < EMB_DIM; ++k) {
    int idx = k * 64 + lane;                     // 0..2111, consecutive per instr
    int e   = (idx * 993) >> 15;                 // idx/33 (exact for idx<2112)
    int j   = idx - e * 33;
    int row = lds_hidx[w][e];
    rowbuf[idx] = emb[(size_t)((long long)row * EMB_DIM + j)];
  }
  __syncthreads();  // B2: head rows staged

  // ---- Rotation + boost + translation on own head row ----
  const float* __restrict__ my = rowbuf + lane * EMB_DIM;
  float x0 = my[0];
  float r[D_];
  #pragma unroll
  for (int q = 0; q < 4; ++q) {
    float4 cv = T[q];
    float4 sv = T[4 + q];
    float cj[4] = {cv.x, cv.y, cv.z, cv.w};
    float sj[4] = {sv.x, sv.y, sv.z, sv.w};
    #pragma unroll
    for (int m = 0; m < 4; ++m) {
      int j = 4 * q + m;
      float a = my[1 + j];
      float b = my[1 + HALF_ + j];
      r[j]         = cj[m] * a - sj[m] * b;
      r[HALF_ + j] = sj[m] * a + cj[m] * b;
    }
  }
  float4 hv = T[16];                 // {cosh(rap), sinh(rap), cosh(vn), -}
  r[0] = fmaf(x0, hv.y, r[0] * hv.x);
  const float cvn = hv.z;

  float rs[D_];
  float n2 = 0.f;
  #pragma unroll
  for (int q = 0; q < 8; ++q) {
    float4 kv = T[8 + q];
    float kj[4] = {kv.x, kv.y, kv.z, kv.w};
    #pragma unroll
    for (int m = 0; m < 4; ++m) {
      int j = 4 * q + m;
      rs[j] = fmaf(cvn, r[j], kj[m]);
      n2 = fmaf(rs[j], rs[j], n2);
    }
  }
  const float ht0 = sqrtf(1.f + n2);

  __syncthreads();  // B3: all head-row LDS reads done, safe to overwrite

  // ---- Phase B: stage 64 tail rows into the same buffer ----
  #pragma unroll
  for (int k = 0; k < EMB_DIM; ++k) {
    int idx = k * 64 + lane;
    int e   = (idx * 993) >> 15;
    int j   = idx - e * 33;
    int row = lds_tidx[w][e];
    rowbuf[idx] = emb[(size_t)((long long)row * EMB_DIM + j)];
  }
  __syncthreads();  // B4: tail rows staged

  const float t0 = my[0];
  float dot = 0.f;
  #pragma unroll
  for (int j = 0; j < D_; ++j) dot = fmaf(rs[j], my[1 + j], dot);

  float neg_inner = fmaf(ht0, t0, -dot);          // -inner
  float ic   = fmaxf(neg_inner, 1.0f + 1e-6f);
  float dist = acoshf(ic);
  if (gid < n) out[gid] = b_h + b_t - dist * dist;
}

// ---------------------------------------------------------------------------
// Fallback (ws too small for tab): fully inline scalar path (R1 kernel).
// ---------------------------------------------------------------------------
__global__ __launch_bounds__(256) void lorentz_fallback_kernel(
    const int* __restrict__ heads, const int* __restrict__ rels,
    const int* __restrict__ tails, const float* __restrict__ emb,
    const float* __restrict__ boost_w, const float* __restrict__ rot_w,
    const float* __restrict__ trans_w, const float* __restrict__ bias,
    float* __restrict__ out, int n) {
  int i = blockIdx.x * blockDim.x + threadIdx.x;
  if (i >= n) return;
  int hd = heads[i], rl = rels[i], tl = tails[i];
  const float* hrow = emb + (size_t)hd * EMB_DIM;
  const float* trow = emb + (size_t)tl * EMB_DIM;
  const float* ro = rot_w   + (size_t)rl * D_;
  const float* tr = trans_w + (size_t)rl * D_;
  float c[HALF_], s[HALF_], kt[D_];
  #pragma unroll
  for (int j = 0; j < HALF_; ++j) { float th = ro[j]; c[j] = cosf(th); s[j] = sinf(th); }
  float s2 = 0.f;
  #pragma unroll
  for (int j = 0; j < D_; ++j) { float v = tr[j]; s2 = fmaf(v, v, s2); }
  float vn = sqrtf(fmaxf(0.01f * s2, 1e-6f));
  float cvn = coshf(vn);
  float k = sinhf(vn) / vn * 0.1f;
  #pragma unroll
  for (int j = 0; j < D_; ++j) kt[j] = k * tr[j];
  float rap = fminf(fmaxf(boost_w[(size_t)rl * D_], -2.f), 2.f);
  float c0 = coshf(rap), s0 = sinhf(rap);
  float x0 = hrow[0];
  float r[D_];
  #pragma unroll
  for (int j = 0; j < HALF_; ++j) {
    float a = hrow[1 + j], b = hrow[1 + HALF_ + j];
    r[j] = c[j] * a - s[j] * b;
    r[HALF_ + j] = s[j] * a + c[j] * b;
  }
  r[0] = fmaf(x0, s0, r[0] * c0);
  float t0 = trow[0], n2 = 0.f, dot = 0.f;
  #pragma unroll
  for (int j = 0; j < D_; ++j) {
    float rsv = fmaf(cvn, r[j], kt[j]);
    n2  = fmaf(rsv, rsv, n2);
    dot = fmaf(rsv, trow[1 + j], dot);
  }
  float ht0 = sqrtf(1.f + n2);
  float neg_inner = fmaf(ht0, t0, -dot);
  float ic = fmaxf(neg_inner, 1.0f + 1e-6f);
  float dist = acoshf(ic);
  out[i] = bias[hd] + bias[tl] - dist * dist;
}

extern "C" void kernel_launch(void* const* d_in, const int* in_sizes, int n_in,
                              void* d_out, int out_size, void* d_ws, size_t ws_size,
                              hipStream_t stream) {
  const int*   heads  = (const int*)d_in[0];
  const int*   rels   = (const int*)d_in[1];
  const int*   tails  = (const int*)d_in[2];
  const float* emb    = (const float*)d_in[3];
  const float* boostw = (const float*)d_in[4];
  const float* rotw   = (const float*)d_in[5];
  const float* transw = (const float*)d_in[6];
  const float* bias   = (const float*)d_in[7];
  float* out = (float*)d_out;
  int n = in_sizes[0];  // B = 1048576

  size_t tab_bytes = (size_t)NR_ * TAB_STRIDE * sizeof(float);
  dim3 block(256);
  dim3 grid((n + 255) / 256);

  if (ws_size >= tab_bytes) {
    float* tab = (float*)d_ws;
    rel_precompute_kernel<<<dim3((NR_ + 255) / 256), block, 0, stream>>>(
        boostw, rotw, transw, tab);
    lorentz_coop_kernel<<<grid, block, 0, stream>>>(
        heads, rels, tails, emb, bias, tab, out, n);
  } else {
    lorentz_fallback_kernel<<<grid, block, 0, stream>>>(
        heads, rels, tails, emb, boostw, rotw, transw, bias, out, n);
  }
}